// Round 1
// baseline (322.285 us; speedup 1.0000x reference)
//
#include <hip/hip_runtime.h>
#include <stdint.h>

// Performer (FAVOR+) attention, fused MFMA implementation for MI355X/gfx950.
//
// Per (b,h): ctx[m][e] = sum_n k'[n][m] v[n][e], s[m] = sum_n k'[n][m],
//            out[n][e] = (sum_m q'[n][m] ctx[m][e]) / (sum_m q'[n][m] s[m])
// with q'/k' = exp(x.P^T - 0.5|x|^2) + 1e-4  (ratio cancels -> dropped).
//
// kernel 1: per (bh, n-chunk) partial ctx/s via f16 MFMA (features) + bf16 MFMA (ctx)
// kernel 2: reduce partials
// kernel 3: q-features + denominator + q'.ctx, normalized store.

#define N_TOK 4096
#define DDIM  64
#define BHCNT 64
#define MFEAT 266
#define M2    272        // 17 tiles of 16 (features padded; pads masked to 0 on k-side)
#define EPS_K 1e-4f

typedef float    f32x4 __attribute__((ext_vector_type(4)));
typedef _Float16 h8    __attribute__((ext_vector_type(8)));
typedef short    s8v   __attribute__((ext_vector_type(8)));
typedef short    s4v   __attribute__((ext_vector_type(4)));

static __device__ __forceinline__ short f2bf(float f) {
  uint32_t u = __float_as_uint(f);
  u = (u + 0x7fffu + ((u >> 16) & 1u)) >> 16;   // RNE
  return (short)u;
}
static __device__ __forceinline__ h8 ldh8(const char* p, int cb, int sw) {
  return *(const h8*)(p + (cb ^ sw));
}
static __device__ __forceinline__ s8v lds8(const char* p, int cb, int sw) {
  return *(const s8v*)(p + (cb ^ sw));
}
#define MFMA_F16(a, b, c)  __builtin_amdgcn_mfma_f32_16x16x32_f16((a), (b), (c), 0, 0, 0)
#define MFMA_BF16(a, b, c) __builtin_amdgcn_mfma_f32_16x16x32_bf16((a), (b), (c), 0, 0, 0)

// ---------------------------------------------------------------------------
// Kernel 1: K-side. 8 waves. Each wave owns m-tiles {wv, wv+8, (wv==0: 16)}.
// Per 64-row tile: stage K (f16, swizzled) + V^T (bf16, swizzled) + diag,
// S = K.P^T (f16 MFMA), exp -> k' written transposed to LDS (wave-private rows),
// ctx_acc += k'^T . V (bf16 MFMA). Partials stored (no atomics).
// ---------------------------------------------------------------------------
__global__ __launch_bounds__(512, 2) void perf_kside(
    const float* __restrict__ Kg, const float* __restrict__ Vg,
    const float* __restrict__ Pg, float* __restrict__ part_ctx,
    float* __restrict__ part_s, int nchunk, int rpc)
{
  __shared__ __attribute__((aligned(16))) short    kpT[M2 * 64];   // bf16 k'^T [m][n], swizzled; init: P f16 [272][64]
  __shared__ __attribute__((aligned(16))) _Float16 klds[64 * 64];  // f16 K tile [n][d], swizzled
  __shared__ __attribute__((aligned(16))) short    vTl[64 * 64];   // bf16 V^T [e][n], swizzled
  __shared__ float diag[64];

  const int tid  = threadIdx.x;
  const int lane = tid & 63;
  const int wv   = tid >> 6;
  const int l15  = lane & 15;
  const int g    = lane >> 4;
  const int bh   = blockIdx.x / nchunk;
  const int ch   = blockIdx.x % nchunk;

  const float* Kb = Kg + (size_t)bh * (N_TOK * DDIM) + (size_t)ch * rpc * DDIM;
  const float* Vb = Vg + (size_t)bh * (N_TOK * DDIM) + (size_t)ch * rpc * DDIM;

  // ---- stage P (fp32 -> f16, plain [272][64], zero pad rows) ----
  _Float16* Pl = (_Float16*)kpT;
  for (int slot = tid; slot < (M2 * DDIM) / 8; slot += 512) {
    int m = slot >> 3, d0 = (slot & 7) * 8;
    h8 v;
    if (m < MFEAT) {
      float4 a = *(const float4*)(Pg + m * DDIM + d0);
      float4 b = *(const float4*)(Pg + m * DDIM + d0 + 4);
      v[0] = (_Float16)a.x; v[1] = (_Float16)a.y; v[2] = (_Float16)a.z; v[3] = (_Float16)a.w;
      v[4] = (_Float16)b.x; v[5] = (_Float16)b.y; v[6] = (_Float16)b.z; v[7] = (_Float16)b.w;
    } else {
      #pragma unroll
      for (int j = 0; j < 8; ++j) v[j] = (_Float16)0.0f;
    }
    *(h8*)(Pl + slot * 8) = v;
  }
  __syncthreads();

  // ---- P fragments -> registers (B operand: col=m=lane&15, k=d=km*32+8g+j) ----
  const int nmt = (wv == 0) ? 3 : 2;
  h8 pf[3][2];
  #pragma unroll
  for (int i = 0; i < 3; ++i) {
    int mt = (i == 2) ? 16 : (wv + 8 * i);
    int m  = mt * 16 + l15;
    #pragma unroll
    for (int km = 0; km < 2; ++km)
      pf[i][km] = *(const h8*)(Pl + m * DDIM + km * 32 + 8 * g);
  }
  __syncthreads();  // P region now reusable as kpT

  const f32x4 z4 = {0.f, 0.f, 0.f, 0.f};
  f32x4 acc[3][4];
  float sacc[3] = {0.f, 0.f, 0.f};
  #pragma unroll
  for (int i = 0; i < 3; ++i)
    #pragma unroll
    for (int e = 0; e < 4; ++e) acc[i][e] = z4;

  const int iters = rpc >> 6;
  for (int it = 0; it < iters; ++it) {
    __syncthreads();  // protect klds/vTl from previous iteration's readers
    {   // ---- stage 64 rows: K->f16 swizzled, diag, V->bf16 transposed swizzled ----
      int r = tid >> 3, c8 = tid & 7, d0 = c8 * 8;
      const float* kr = Kb + (size_t)(it * 64 + r) * DDIM + d0;
      float4 a = *(const float4*)kr;
      float4 b = *(const float4*)(kr + 4);
      float ss = a.x*a.x + a.y*a.y + a.z*a.z + a.w*a.w
               + b.x*b.x + b.y*b.y + b.z*b.z + b.w*b.w;
      ss += __shfl_xor(ss, 1); ss += __shfl_xor(ss, 2); ss += __shfl_xor(ss, 4);
      if (c8 == 0) diag[r] = 0.5f * ss;
      h8 kv;
      kv[0] = (_Float16)a.x; kv[1] = (_Float16)a.y; kv[2] = (_Float16)a.z; kv[3] = (_Float16)a.w;
      kv[4] = (_Float16)b.x; kv[5] = (_Float16)b.y; kv[6] = (_Float16)b.z; kv[7] = (_Float16)b.w;
      *(h8*)((char*)klds + r * 128 + ((16 * c8) ^ ((r & 7) << 4))) = kv;
      const float* vr = Vb + (size_t)(it * 64 + r) * DDIM + d0;
      float4 va = *(const float4*)vr;
      float4 vb = *(const float4*)(vr + 4);
      float vv[8] = {va.x, va.y, va.z, va.w, vb.x, vb.y, vb.z, vb.w};
      #pragma unroll
      for (int j = 0; j < 8; ++j) {
        int e = d0 + j;
        *(short*)((char*)vTl + e * 128 + ((2 * r) ^ ((e & 7) << 4))) = f2bf(vv[j]);
      }
    }
    __syncthreads();

    // ---- S = K.P^T per n-tile, exp epilogue, write k'^T (wave-private rows) ----
    #pragma unroll
    for (int nt = 0; nt < 4; ++nt) {
      int n = nt * 16 + l15;
      const char* arow = (const char*)klds + n * 128;
      int swn = (n & 7) << 4;
      h8 a0 = ldh8(arow, 16 * g, swn);
      h8 a1 = ldh8(arow, 64 + 16 * g, swn);
      float dg[4];
      #pragma unroll
      for (int rr = 0; rr < 4; ++rr) dg[rr] = diag[nt * 16 + 4 * g + rr];
      #pragma unroll
      for (int i = 0; i < 3; ++i) {
        if (i >= nmt) continue;
        int mt = (i == 2) ? 16 : (wv + 8 * i);
        int m  = mt * 16 + l15;
        f32x4 sc = z4;
        sc = MFMA_F16(a0, pf[i][0], sc);
        sc = MFMA_F16(a1, pf[i][1], sc);
        float e0 = __expf(sc[0] - dg[0]) + EPS_K;
        float e1 = __expf(sc[1] - dg[1]) + EPS_K;
        float e2 = __expf(sc[2] - dg[2]) + EPS_K;
        float e3 = __expf(sc[3] - dg[3]) + EPS_K;
        if (m >= MFEAT) { e0 = 0.f; e1 = 0.f; e2 = 0.f; e3 = 0.f; }
        sacc[i] += (e0 + e1) + (e2 + e3);
        s4v kq; kq[0] = f2bf(e0); kq[1] = f2bf(e1); kq[2] = f2bf(e2); kq[3] = f2bf(e3);
        *(s4v*)((char*)kpT + m * 128 + ((32 * nt + 8 * g) ^ ((m & 7) << 4))) = kq;
      }
    }

    // ---- ctx_acc += k'^T . V (rows of kpT are wave-private; no barrier needed) ----
    s8v Bf[4][2];
    #pragma unroll
    for (int et = 0; et < 4; ++et) {
      int e = et * 16 + l15;
      const char* brow = (const char*)vTl + e * 128;
      int swe = (e & 7) << 4;
      Bf[et][0] = lds8(brow, 16 * g, swe);
      Bf[et][1] = lds8(brow, 64 + 16 * g, swe);
    }
    #pragma unroll
    for (int i = 0; i < 3; ++i) {
      if (i >= nmt) continue;
      int mt = (i == 2) ? 16 : (wv + 8 * i);
      int m  = mt * 16 + l15;
      const char* arow = (const char*)kpT + m * 128;
      int swm = (m & 7) << 4;
      s8v A0 = lds8(arow, 16 * g, swm);
      s8v A1 = lds8(arow, 64 + 16 * g, swm);
      #pragma unroll
      for (int et = 0; et < 4; ++et) {
        acc[i][et] = MFMA_BF16(A0, Bf[et][0], acc[i][et]);
        acc[i][et] = MFMA_BF16(A1, Bf[et][1], acc[i][et]);
      }
    }
  }

  // ---- store chunk partials ----
  float* pc = part_ctx + ((size_t)bh * nchunk + ch) * (M2 * DDIM);
  #pragma unroll
  for (int i = 0; i < 3; ++i) {
    if (i >= nmt) continue;
    int mt = (i == 2) ? 16 : (wv + 8 * i);
    #pragma unroll
    for (int et = 0; et < 4; ++et) {
      #pragma unroll
      for (int rr = 0; rr < 4; ++rr) {
        int m = mt * 16 + 4 * g + rr;
        pc[m * DDIM + et * 16 + l15] = acc[i][et][rr];
      }
    }
  }
  float* ps = part_s + ((size_t)bh * nchunk + ch) * M2;
  #pragma unroll
  for (int i = 0; i < 3; ++i) {
    if (i >= nmt) continue;
    int mt = (i == 2) ? 16 : (wv + 8 * i);
    float v = sacc[i];
    v += __shfl_xor(v, 16);
    v += __shfl_xor(v, 32);
    if (lane < 16) ps[mt * 16 + lane] = v;
  }
}

// ---------------------------------------------------------------------------
// Kernel 2: reduce chunk partials -> final ctx [bh][272][64] and s [bh][272].
// ---------------------------------------------------------------------------
__global__ void perf_reduce(const float* __restrict__ part_ctx,
                            const float* __restrict__ part_s,
                            float* __restrict__ ctxg, float* __restrict__ sveca,
                            int nchunk)
{
  int idx = blockIdx.x * 256 + threadIdx.x;
  const int tot_c = BHCNT * M2 * DDIM;
  if (idx < tot_c) {
    int bh = idx / (M2 * DDIM);
    int me = idx - bh * (M2 * DDIM);
    float s = 0.f;
    for (int c = 0; c < nchunk; ++c)
      s += part_ctx[((size_t)bh * nchunk + c) * (M2 * DDIM) + me];
    ctxg[idx] = s;
  } else {
    int j = idx - tot_c;
    if (j < BHCNT * M2) {
      int bh = j / M2;
      int m  = j - bh * M2;
      float s = 0.f;
      for (int c = 0; c < nchunk; ++c)
        s += part_s[((size_t)bh * nchunk + c) * M2 + m];
      sveca[j] = s;
    }
  }
}

// ---------------------------------------------------------------------------
// Kernel 3: Q-side. ctx^T staged once in LDS (bf16, [e][296] padded rows).
// Per 64-row tile: stage Q, S = Q.P^T (waves split by m), exp -> q' [n][296],
// denominator via fp32 VALU + shfl + LDS atomic; then out = q'.ctx / den
// (waves split by (n-tile, e-pair); A fragment shared across its 2 e-tiles).
// ---------------------------------------------------------------------------
__global__ __launch_bounds__(512, 2) void perf_qside(
    const float* __restrict__ Qg, const float* __restrict__ Pg,
    const float* __restrict__ ctxg, const float* __restrict__ sveca,
    float* __restrict__ Og)
{
  __shared__ __attribute__((aligned(16))) short ctxT[64 * 296];   // bf16 ctx^T [e][m] padded
  __shared__ __attribute__((aligned(16))) char  reg1[47168];      // P init | q' + ql + s_l
  __shared__ float dia[64];
  __shared__ float den[64];

  short*    qp  = (short*)reg1;                 // [64][296] bf16 q'
  _Float16* ql  = (_Float16*)(reg1 + 37888);    // [64][64] f16 Q tile, swizzled
  float*    s_l = (float*)(reg1 + 46080);       // [272] fp32 k_cumsum

  const int tid  = threadIdx.x;
  const int lane = tid & 63;
  const int wv   = tid >> 6;
  const int l15  = lane & 15;
  const int g    = lane >> 4;
  const int bh   = blockIdx.x >> 2;
  const int ch   = blockIdx.x & 3;

  const float* Qb = Qg + (size_t)bh * (N_TOK * DDIM) + (size_t)ch * 1024 * DDIM;
  float*       Ob = Og + (size_t)bh * (N_TOK * DDIM) + (size_t)ch * 1024 * DDIM;

  // ---- stage P (f16 [272][64]) into q' region ----
  _Float16* Pl = (_Float16*)reg1;
  for (int slot = tid; slot < (M2 * DDIM) / 8; slot += 512) {
    int m = slot >> 3, d0 = (slot & 7) * 8;
    h8 v;
    if (m < MFEAT) {
      float4 a = *(const float4*)(Pg + m * DDIM + d0);
      float4 b = *(const float4*)(Pg + m * DDIM + d0 + 4);
      v[0] = (_Float16)a.x; v[1] = (_Float16)a.y; v[2] = (_Float16)a.z; v[3] = (_Float16)a.w;
      v[4] = (_Float16)b.x; v[5] = (_Float16)b.y; v[6] = (_Float16)b.z; v[7] = (_Float16)b.w;
    } else {
      #pragma unroll
      for (int j = 0; j < 8; ++j) v[j] = (_Float16)0.0f;
    }
    *(h8*)(Pl + slot * 8) = v;
  }
  __syncthreads();

  const int nmt = (wv == 0) ? 3 : 2;
  h8 pf[3][2];
  #pragma unroll
  for (int i = 0; i < 3; ++i) {
    int mt = (i == 2) ? 16 : (wv + 8 * i);
    int m  = mt * 16 + l15;
    #pragma unroll
    for (int km = 0; km < 2; ++km)
      pf[i][km] = *(const h8*)(Pl + m * DDIM + km * 32 + 8 * g);
  }
  __syncthreads();  // P region now reusable

  // ---- stage ctx^T (bf16, zero pads) + s ----
  const float* cbp = ctxg + (size_t)bh * (M2 * DDIM);
  for (int slot = tid; slot < 64 * 296; slot += 512) {
    int e = slot / 296, m = slot - e * 296;
    float v = (m < M2) ? cbp[(size_t)m * DDIM + e] : 0.f;
    ctxT[e * 296 + m] = f2bf(v);
  }
  for (int m = tid; m < M2; m += 512) s_l[m] = sveca[bh * M2 + m];
  __syncthreads();

  const f32x4 z4 = {0.f, 0.f, 0.f, 0.f};
  for (int it = 0; it < 16; ++it) {
    __syncthreads();  // protect q'/ql/dia/den from previous iteration readers
    {   // ---- stage Q tile + diag; zero den; zero q' pad columns ----
      int r = tid >> 3, c8 = tid & 7, d0 = c8 * 8;
      const float* qr = Qb + (size_t)(it * 64 + r) * DDIM + d0;
      float4 a = *(const float4*)qr;
      float4 b = *(const float4*)(qr + 4);
      float ss = a.x*a.x + a.y*a.y + a.z*a.z + a.w*a.w
               + b.x*b.x + b.y*b.y + b.z*b.z + b.w*b.w;
      ss += __shfl_xor(ss, 1); ss += __shfl_xor(ss, 2); ss += __shfl_xor(ss, 4);
      if (c8 == 0) { dia[r] = 0.5f * ss; den[r] = 0.f; }
      h8 qv;
      qv[0] = (_Float16)a.x; qv[1] = (_Float16)a.y; qv[2] = (_Float16)a.z; qv[3] = (_Float16)a.w;
      qv[4] = (_Float16)b.x; qv[5] = (_Float16)b.y; qv[6] = (_Float16)b.z; qv[7] = (_Float16)b.w;
      *(h8*)((char*)ql + r * 128 + ((16 * c8) ^ ((r & 7) << 4))) = qv;
      int pc2 = 272 + 2 * c8;
      qp[r * 296 + pc2] = 0;
      qp[r * 296 + pc2 + 1] = 0;
    }
    __syncthreads();

    // ---- S = Q.P^T, exp, q' write, denominator partials ----
    #pragma unroll
    for (int nt = 0; nt < 4; ++nt) {
      int n = nt * 16 + l15;
      const char* arow = (const char*)ql + n * 128;
      int swn = (n & 7) << 4;
      h8 a0 = ldh8(arow, 16 * g, swn);
      h8 a1 = ldh8(arow, 64 + 16 * g, swn);
      float dg[4];
      #pragma unroll
      for (int rr = 0; rr < 4; ++rr) dg[rr] = dia[nt * 16 + 4 * g + rr];
      float dl0 = 0.f, dl1 = 0.f, dl2 = 0.f, dl3 = 0.f;
      #pragma unroll
      for (int i = 0; i < 3; ++i) {
        if (i >= nmt) continue;
        int mt = (i == 2) ? 16 : (wv + 8 * i);
        int m  = mt * 16 + l15;
        f32x4 sc = z4;
        sc = MFMA_F16(a0, pf[i][0], sc);
        sc = MFMA_F16(a1, pf[i][1], sc);
        float sm = s_l[m];
        float e0 = __expf(sc[0] - dg[0]) + EPS_K;
        float e1 = __expf(sc[1] - dg[1]) + EPS_K;
        float e2 = __expf(sc[2] - dg[2]) + EPS_K;
        float e3 = __expf(sc[3] - dg[3]) + EPS_K;
        // no masking needed: ctx/s are zero for m >= 266
        short* qcol = qp + m;
        qcol[(nt * 16 + 4 * g + 0) * 296] = f2bf(e0);
        qcol[(nt * 16 + 4 * g + 1) * 296] = f2bf(e1);
        qcol[(nt * 16 + 4 * g + 2) * 296] = f2bf(e2);
        qcol[(nt * 16 + 4 * g + 3) * 296] = f2bf(e3);
        dl0 += e0 * sm; dl1 += e1 * sm; dl2 += e2 * sm; dl3 += e3 * sm;
      }
      dl0 += __shfl_xor(dl0, 1); dl0 += __shfl_xor(dl0, 2); dl0 += __shfl_xor(dl0, 4); dl0 += __shfl_xor(dl0, 8);
      dl1 += __shfl_xor(dl1, 1); dl1 += __shfl_xor(dl1, 2); dl1 += __shfl_xor(dl1, 4); dl1 += __shfl_xor(dl1, 8);
      dl2 += __shfl_xor(dl2, 1); dl2 += __shfl_xor(dl2, 2); dl2 += __shfl_xor(dl2, 4); dl2 += __shfl_xor(dl2, 8);
      dl3 += __shfl_xor(dl3, 1); dl3 += __shfl_xor(dl3, 2); dl3 += __shfl_xor(dl3, 4); dl3 += __shfl_xor(dl3, 8);
      if (l15 == 0) {
        atomicAdd(&den[nt * 16 + 4 * g + 0], dl0);
        atomicAdd(&den[nt * 16 + 4 * g + 1], dl1);
        atomicAdd(&den[nt * 16 + 4 * g + 2], dl2);
        atomicAdd(&den[nt * 16 + 4 * g + 3], dl3);
      }
    }
    __syncthreads();

    // ---- out tile: wave -> (nt = wv>>1, e-tiles {2*(wv&1), 2*(wv&1)+1}) ----
    {
      int nt4 = wv >> 1, eb = (wv & 1) * 2;
      const char* arow = (const char*)(qp + (nt4 * 16 + l15) * 296);
      const char* br0  = (const char*)(ctxT + ((eb    ) * 16 + l15) * 296);
      const char* br1  = (const char*)(ctxT + ((eb + 1) * 16 + l15) * 296);
      f32x4 o0 = z4, o1 = z4;
      #pragma unroll
      for (int ks = 0; ks < 9; ++ks) {
        int cbyte = ks * 64 + 16 * g;
        s8v A  = *(const s8v*)(arow + cbyte);
        s8v B0 = *(const s8v*)(br0 + cbyte);
        s8v B1 = *(const s8v*)(br1 + cbyte);
        o0 = MFMA_BF16(A, B0, o0);
        o1 = MFMA_BF16(A, B1, o1);
      }
      #pragma unroll
      for (int rr = 0; rr < 4; ++rr) {
        int n = nt4 * 16 + 4 * g + rr;
        float dv = 1.0f / den[n];
        float* orow = Ob + (size_t)(it * 64 + n) * DDIM;
        orow[eb * 16 + l15]      = o0[rr] * dv;
        orow[eb * 16 + 16 + l15] = o1[rr] * dv;
      }
    }
  }
}

// ---------------------------------------------------------------------------
extern "C" void kernel_launch(void* const* d_in, const int* in_sizes, int n_in,
                              void* d_out, int out_size, void* d_ws, size_t ws_size,
                              hipStream_t stream)
{
  const float* q = (const float*)d_in[0];
  const float* k = (const float*)d_in[1];
  const float* v = (const float*)d_in[2];
  const float* p = (const float*)d_in[3];
  float* out = (float*)d_out;
  (void)in_sizes; (void)n_in; (void)out_size;

  // ws: [part_ctx BH*nch*272*64][part_s BH*nch*272][ctx BH*272*64][s BH*272] (fp32)
  int nch = 8;
  while (nch > 1) {
    size_t need = (size_t)4 * ((size_t)BHCNT * nch * (M2 * DDIM) + (size_t)BHCNT * nch * M2
                               + (size_t)BHCNT * (M2 * DDIM) + (size_t)BHCNT * M2);
    if (need <= ws_size) break;
    nch >>= 1;
  }
  float* part_ctx = (float*)d_ws;
  float* part_s   = part_ctx + (size_t)BHCNT * nch * (M2 * DDIM);
  float* ctxg     = part_s   + (size_t)BHCNT * nch * M2;
  float* sveca    = ctxg     + (size_t)BHCNT * (M2 * DDIM);

  perf_kside<<<dim3(BHCNT * nch), dim3(512), 0, stream>>>(k, v, p, part_ctx, part_s,
                                                          nch, N_TOK / nch);
  int redn = (BHCNT * M2 * DDIM + BHCNT * M2 + 255) / 256;
  perf_reduce<<<dim3(redn), dim3(256), 0, stream>>>(part_ctx, part_s, ctxg, sveca, nch);
  perf_qside<<<dim3(BHCNT * 4), dim3(512), 0, stream>>>(q, p, ctxg, sveca, out);
}